// Round 1
// baseline (59.649 us; speedup 1.0000x reference)
//
#include <hip/hip_runtime.h>

// IAF spiking layer: data (B*T, F) fp32, B=32, T=1024, F=1024.
// Per chain (b, f):
//   s = (x_t + s) - a            (THRESHOLD = 1)
//   s = max(s + 1, 0) - 1        (clamp at THRESHOLD_LOW = -1, exact ref op order)
//   a = (s > 0) ? floor(s) : 0
//   out[(b*T + t)*F + f] = a
// t is sequential; chains are independent. Coalesced: lane f reads/writes
// consecutive addresses at each t (row stride F between steps).

constexpr int T = 1024;
constexpr int F = 1024;
constexpr int D = 16;        // prefetch chunk depth (register double buffer)
constexpr int NC = T / D;    // 64 chunks

__global__ __launch_bounds__(64) void iaf_kernel(const float* __restrict__ x,
                                                 float* __restrict__ out) {
    const int tid = blockIdx.x * 64 + threadIdx.x;   // 0..32767
    const int b = tid >> 10;                          // tid / F
    const int f = tid & (F - 1);
    const size_t base = (size_t)b * T * F + f;
    const float* __restrict__ p = x + base;
    float* __restrict__ q = out + base;

    float bufA[D], bufB[D];   // statically indexed only -> stays in VGPRs
    float s = 0.0f, a = 0.0f;

    // prologue: chunk 0 -> A
#pragma unroll
    for (int i = 0; i < D; ++i) bufA[i] = p[(size_t)i * F];

    for (int c = 0; c < NC; c += 2) {
        // prefetch chunk c+1 -> B (independent of recurrence; stays in flight
        // while we compute chunk c)
#pragma unroll
        for (int i = 0; i < D; ++i)
            bufB[i] = p[(size_t)((c + 1) * D + i) * F];

        // compute chunk c from A
#pragma unroll
        for (int i = 0; i < D; ++i) {
            const float xv = bufA[i];
            s = (xv + s) - a;
            s = fmaxf(s + 1.0f, 0.0f) - 1.0f;   // exact ref order: relu(s-(-1)) + (-1)
            a = (s > 0.0f) ? floorf(s) : 0.0f;
            q[(size_t)(c * D + i) * F] = a;
        }

        // prefetch chunk c+2 -> A
        if (c + 2 < NC) {
#pragma unroll
            for (int i = 0; i < D; ++i)
                bufA[i] = p[(size_t)((c + 2) * D + i) * F];
        }

        // compute chunk c+1 from B
#pragma unroll
        for (int i = 0; i < D; ++i) {
            const float xv = bufB[i];
            s = (xv + s) - a;
            s = fmaxf(s + 1.0f, 0.0f) - 1.0f;
            a = (s > 0.0f) ? floorf(s) : 0.0f;
            q[(size_t)((c + 1) * D + i) * F] = a;
        }
    }
}

extern "C" void kernel_launch(void* const* d_in, const int* in_sizes, int n_in,
                              void* d_out, int out_size, void* d_ws, size_t ws_size,
                              hipStream_t stream) {
    const float* x = (const float*)d_in[0];
    float* out = (float*)d_out;
    // 32 * 1024 chains, one thread each; 64-thread blocks -> 512 blocks
    // (2 blocks/CU on 256 CUs; ILP prefetch hides HBM latency at low occupancy)
    iaf_kernel<<<dim3(512), dim3(64), 0, stream>>>(x, out);
}

// Round 2
// 44.575 us; speedup vs baseline: 1.3382x; 1.3382x over previous
//
#include <hip/hip_runtime.h>
#include <stdint.h>

// IAF spiking layer: data (B*T, F) fp32, B=32, T=1024, F=1024.
// One thread per (b,f) chain; t strictly sequential.
// Parallelism is capped at 32768 threads (2 waves/CU), so latency hiding
// comes from a guaranteed-deep global_load_lds pipeline with counted vmcnt
// waits (never 0) — the compiler cannot collapse it (no VGPR destination).
//
// Chunking: DEPTH=16 t-steps per chunk, staged into a 4-buffer LDS ring by
// 4x 16B-per-lane global_load_lds per chunk (lane -> row=lane>>4,
// col=(lane&15)*4; LDS dest linear). 3 chunks prefetched ahead = 12 KB/wave
// in flight -> 24 KB/CU > BW*latency (~12 KB/CU) needed to saturate HBM.
//
// vmcnt accounting (4 load-insts + 16 store-insts per chunk, issue order
// pinned by sched_barrier(0) + asm memory clobbers):
//   iter c ops issued after L(c): S(c-3 later ones)... steady = 56
//   prologue peels: 8, 24, 40; tail peels: 48, 48.

constexpr int T = 1024;
constexpr int F = 1024;
constexpr int DEPTH = 16;               // t-steps per chunk
constexpr int NC = T / DEPTH;           // 64 chunks
constexpr int CHUNK_FLOATS = DEPTH * 64; // 1024 floats = 4 KB per buffer

#define WAITVM(N) asm volatile("s_waitcnt vmcnt(" #N ")" ::: "memory")

__global__ __launch_bounds__(64) void iaf_kernel(const float* __restrict__ x,
                                                 float* __restrict__ out) {
    __shared__ float lds[4 * CHUNK_FLOATS];   // 16 KB ring (4 buffers)

    const int lane = threadIdx.x;             // 0..63
    const int b = blockIdx.x >> 4;            // 32 batch rows
    const int f0 = (blockIdx.x & 15) * 64;    // feature block base

    const size_t base = ((size_t)b * T) * F + f0;
    const float* __restrict__ p = x + base;   // row t at p + t*F
    float* __restrict__ q = out + base + lane;

    // per-lane source mapping for the 16B global_load_lds:
    // instruction r (r=0..3) of chunk k covers rows k*16 + r*4 + (lane>>4),
    // bytes [(lane&15)*16, +16) of that row. LDS dest = base + lane*16
    // (hardware-defined, linear) == row-major [16][64] float tile.
    const int lrow = lane >> 4;        // 0..3
    const int lcol = (lane & 15) * 4;  // float offset within row

    float s = 0.0f, a = 0.0f;

    auto issue_chunk = [&](int k) {
        float* lb = &lds[(k & 3) * CHUNK_FLOATS];
#pragma unroll
        for (int r = 0; r < 4; ++r) {
            const float* gsrc = p + (size_t)(k * DEPTH + r * 4 + lrow) * F + lcol;
            __builtin_amdgcn_global_load_lds(
                (const __attribute__((address_space(1))) void*)gsrc,
                (__attribute__((address_space(3))) void*)(lb + r * 256),
                16, 0, 0);
        }
        // pin issue order: loads must precede this iteration's stores,
        // otherwise the vmcnt counting below is wrong.
        __builtin_amdgcn_sched_barrier(0);
    };

    auto compute_chunk = [&](int k) {
        const float* lb = &lds[(k & 3) * CHUNK_FLOATS];
        float xv[DEPTH];
#pragma unroll
        for (int i = 0; i < DEPTH; ++i) xv[i] = lb[i * 64 + lane];
#pragma unroll
        for (int i = 0; i < DEPTH; ++i) {
            // exact reference op order (bit-exact floor/relu feedback):
            s = (xv[i] + s) - a;
            s = fmaxf(s + 1.0f, 0.0f) - 1.0f;    // relu(s - (-1)) + (-1)
            a = (s > 0.0f) ? floorf(s) : 0.0f;
            q[(size_t)(k * DEPTH + i) * F] = a;
        }
    };

    // prologue: 3 chunks in flight
    issue_chunk(0);
    issue_chunk(1);
    issue_chunk(2);

    // peeled iterations with exact vmcnt counts
    WAITVM(8);  issue_chunk(3); compute_chunk(0);
    WAITVM(24); issue_chunk(4); compute_chunk(1);
    WAITVM(40); issue_chunk(5); compute_chunk(2);

    // steady state: ops issued after L(c) = 3*16 stores + 2*4 loads = 56
    for (int c = 3; c <= 61; ++c) {
        WAITVM(56);
        if (c <= 60) issue_chunk(c + 3);
        compute_chunk(c);
    }

    // tail: fewer loads outstanding -> tighter (conservative-safe) counts
    WAITVM(48); compute_chunk(62);
    WAITVM(48); compute_chunk(63);
}

extern "C" void kernel_launch(void* const* d_in, const int* in_sizes, int n_in,
                              void* d_out, int out_size, void* d_ws, size_t ws_size,
                              hipStream_t stream) {
    const float* x = (const float*)d_in[0];
    float* out = (float*)d_out;
    // 512 blocks x 64 threads = 32768 chains (one per (b,f)); 2 waves/CU.
    iaf_kernel<<<dim3(512), dim3(64), 0, stream>>>(x, out);
}